// Round 9
// baseline (374.932 us; speedup 1.0000x reference)
//
#include <hip/hip_runtime.h>
#include <hip/hip_bf16.h>

// Transformer block B=4096,T=64,C=64,H=8,hs=8,FF=256. fp32 in/out, bf16 MFMA.
// One batch/block, 4 waves; wave w owns rows t in [16w,16w+16).
// mfma_f32_16x16x32_bf16: C col=lane&15,row=quad*4+reg; A[m=lane&15][k=quad*8+j];
// B[k=quad*8+j][n=lane&15]. A-frag and B-frag share the same lane->W[k][col] map.
// R14 = R9 revert + CORRECTNESS FIX. R10-R12's P stride 40 < 64 s-extent made
// row t's s>=40 alias row t+1's s-24 (masked zeros overwrote real P for waves
// 2-3, +23-short OOB on row 63) — passed only via loose absmax threshold
// (0.033 clean -> 0.086 corrupted). P restored to stride 72, single buffer
// (correct ping-pong costs 46KB -> 3 blocks/CU, net loss). Numerics-neutral
// reorders kept: k/v before q in phase 2 (stores drain under q MFMAs), bq8
// hoist (32 bpermutes pipelined ahead of head loop). LDS 37008B, 4 blocks/CU.
// Barriers: 7.

typedef __attribute__((ext_vector_type(8))) short short8;
typedef __attribute__((ext_vector_type(4))) float f32x4;

#if __has_builtin(__builtin_amdgcn_exp2f)
#define EXP2F(x) __builtin_amdgcn_exp2f(x)
#else
#define EXP2F(x) __expf((x) * 0.69314718056f)
#endif
#if __has_builtin(__builtin_amdgcn_rcpf)
#define RCPF(x) __builtin_amdgcn_rcpf(x)
#else
#define RCPF(x) (1.0f / (x))
#endif

#define ST  72           // row stride in shorts (144 B) for h/k/vT/P
#define STU 136          // u chunk row stride (272 B)
#define OH  0            // h(LN1) [64][ST]; then a16; then y cols 0..31 (f32 [64][34])
#define OKK 4608         // k [64][ST]
#define OV  9216         // vT rows 0..63 + ones row 64 (65 x ST, ends 13896)
#define OP  13896        // P [64][ST] single; later h2; later y cols 32..63 (f32 [64][34])
#define OU  4608         // u chunk [64][STU] (overlays k,vT after attention; ends 13312)
#define NSH 18504        // shorts = 37008 B -> 4 blocks/CU

__device__ __forceinline__ short f2bf(float f) {
    unsigned int u = __float_as_uint(f);
    u += 0x7fffu + ((u >> 16) & 1u);
    return (short)(u >> 16);
}
__device__ __forceinline__ unsigned pk2(float a, float b) {
    float2 t; t.x = a; t.y = b;
    __hip_bfloat162 h = __float22bfloat162_rn(t);
    unsigned u; __builtin_memcpy(&u, &h, 4); return u;
}
__device__ __forceinline__ f32x4 mfma16(short8 a, short8 b, f32x4 c) {
    return __builtin_amdgcn_mfma_f32_16x16x32_bf16(a, b, c, 0, 0, 0);
}

// ---- weight pre-pack: fp32 -> bf16 frag order (Wq pre-scaled by 1/8*log2e) ----
// fid 0..23: QKV (tile*2+ks; 0..3 Wq,4..7 Wk,8..11 Wv); 24..31: Wo; 32..63: W1; 64..95: W2
__global__ __launch_bounds__(64) void prepack_kernel(
    const float* __restrict__ Wq, const float* __restrict__ Wk,
    const float* __restrict__ Wv, const float* __restrict__ Wo,
    const float* __restrict__ W1, const float* __restrict__ W2,
    short* __restrict__ ws)
{
    int gid = blockIdx.x * 64 + threadIdx.x;       // 96 blocks * 64 = 96 fids * 64 lanes
    int lane = gid & 63;
    int fid  = gid >> 6;
    int quad = lane >> 4, nn = lane & 15;
    short8 o;
    if (fid < 24) {
        int tile = fid >> 1, ks = fid & 1;
        const float* Ws = (tile < 4) ? Wq : ((tile < 8) ? Wk : Wv);
        float scale = (tile < 4) ? 0.18033688011f : 1.0f;   // 1/8 * log2(e) folded into q
        int col = (tile & 3) * 16 + nn;
#pragma unroll
        for (int j = 0; j < 8; ++j)
            o[j] = f2bf(Ws[(ks * 32 + quad * 8 + j) * 64 + col] * scale);
    } else if (fid < 32) {
        int idx = fid - 24, nt = idx >> 1, ks = idx & 1;
#pragma unroll
        for (int j = 0; j < 8; ++j)
            o[j] = f2bf(Wo[(ks * 32 + quad * 8 + j) * 64 + nt * 16 + nn]);
    } else if (fid < 64) {
        int idx = fid - 32, c = idx >> 3, tile = (idx >> 1) & 3, ks = idx & 1;
#pragma unroll
        for (int j = 0; j < 8; ++j)
            o[j] = f2bf(W1[(ks * 32 + quad * 8 + j) * 256 + c * 64 + tile * 16 + nn]);
    } else {
        int idx = fid - 64, c = idx >> 3, nt = (idx >> 1) & 3, ks = idx & 1;
#pragma unroll
        for (int j = 0; j < 8; ++j)
            o[j] = f2bf(W2[(c * 64 + ks * 32 + quad * 8 + j) * 64 + nt * 16 + nn]);
    }
    *(short8*)(ws + (size_t)gid * 8) = o;
}

__global__ __launch_bounds__(256, 4) void block_kernel(
    const float* __restrict__ x,
    const float* __restrict__ bo,
    const float* __restrict__ b1,
    const float* __restrict__ b2,
    const float* __restrict__ g1, const float* __restrict__ be1,
    const float* __restrict__ g2, const float* __restrict__ be2,
    const short8* __restrict__ WB,
    float* __restrict__ out)
{
    __shared__ short sm[NSH];
    const int tid  = threadIdx.x;
    const int wv   = tid >> 6;
    const int lane = tid & 63;
    const int quad = lane >> 4;
    const int nn   = lane & 15;
    const int t_my = wv * 16 + nn;        // column-owned row index for swapped products
    const int b    = blockIdx.x;
    const float* xb = x + (size_t)b * 4096;
    const f32x4 zf = {0.f, 0.f, 0.f, 0.f};
    const short8 z8 = {0, 0, 0, 0, 0, 0, 0, 0};

    // ---------- phase 1: x -> regs (C-layout), LN1 -> h; init ones row ----------
    if (tid < ST) sm[OV + 64 * ST + tid] = (short)0x3F80;   // ones row (m=8 of PV A)
    float xr[16];                          // xr[nt*4+r] = x[16wv+quad*4+r][nt*16+nn]
    float gv[4], bv[4];
#pragma unroll
    for (int nt = 0; nt < 4; ++nt) { gv[nt] = g1[nt * 16 + nn]; bv[nt] = be1[nt * 16 + nn]; }
#pragma unroll
    for (int nt = 0; nt < 4; ++nt)
#pragma unroll
        for (int r = 0; r < 4; ++r)
            xr[nt * 4 + r] = xb[(wv * 16 + quad * 4 + r) * 64 + nt * 16 + nn];
#pragma unroll
    for (int r = 0; r < 4; ++r) {
        float s1 = 0.f, s2 = 0.f;
#pragma unroll
        for (int nt = 0; nt < 4; ++nt) { float v = xr[nt * 4 + r]; s1 += v; s2 += v * v; }
        s1 += __shfl_xor(s1, 1); s1 += __shfl_xor(s1, 2); s1 += __shfl_xor(s1, 4); s1 += __shfl_xor(s1, 8);
        s2 += __shfl_xor(s2, 1); s2 += __shfl_xor(s2, 2); s2 += __shfl_xor(s2, 4); s2 += __shfl_xor(s2, 8);
        float mu = s1 * 0.015625f;
        float rstd = rsqrtf(s2 * 0.015625f - mu * mu + 1e-5f);
        int base = OH + (wv * 16 + quad * 4 + r) * ST + nn;
        float h0 = (xr[0 + r]  - mu) * rstd * gv[0] + bv[0];
        float h1 = (xr[4 + r]  - mu) * rstd * gv[1] + bv[1];
        float h2 = (xr[8 + r]  - mu) * rstd * gv[2] + bv[2];
        float h3 = (xr[12 + r] - mu) * rstd * gv[3] + bv[3];
        unsigned pA = pk2(h0, h1), pB = pk2(h2, h3);
        sm[base +  0] = (short)pA;
        sm[base + 16] = (short)(pA >> 16);
        sm[base + 32] = (short)pB;
        sm[base + 48] = (short)(pB >> 16);
    }
    __syncthreads();   // B0: h visible to all waves (k/v col-partition reads all rows)

    // ---------- phase 2: k/v (LDS, col-part: 2 frags each), then q (regs) ----------
    unsigned qp[8];                        // qp[jt*2+p] = bf16 pair q[t_my][jt*16+quad*4+2p..+1]
    {
        // weight frags for this wave's k/v column slice: load ONCE, reuse over 4 row-tiles
        const short8 wk0 = WB[(size_t)((4 + wv) * 2 + 0) * 64 + lane];
        const short8 wk1 = WB[(size_t)((4 + wv) * 2 + 1) * 64 + lane];
        const short8 wv0 = WB[(size_t)((8 + wv) * 2 + 0) * 64 + lane];
        const short8 wv1 = WB[(size_t)((8 + wv) * 2 + 1) * 64 + lane];
#pragma unroll
        for (int rt = 0; rt < 4; ++rt) {           // k,v for ALL rows, own col-slice
            short8 hA = *(const short8*)&sm[OH + (rt * 16 + nn) * ST + quad * 8];
            short8 hB = *(const short8*)&sm[OH + (rt * 16 + nn) * ST + 32 + quad * 8];
            // k cols wv*16..+15: C[m=kcol][n=t] -> store k[t][kcol]
            f32x4 ka = mfma16(wk0, hA, zf); ka = mfma16(wk1, hB, ka);
            uint2 w1; w1.x = pk2(ka[0], ka[1]); w1.y = pk2(ka[2], ka[3]);
            *(uint2*)&sm[OKK + (rt * 16 + nn) * ST + wv * 16 + quad * 4] = w1;
            // v cols wv*16..+15: C[m=t][n=vcol] -> store vT[vcol][t]
            f32x4 va = mfma16(hA, wv0, zf); va = mfma16(hB, wv1, va);
            uint2 w2; w2.x = pk2(va[0], va[1]); w2.y = pk2(va[2], va[3]);
            *(uint2*)&sm[OV + (wv * 16 + nn) * ST + rt * 16 + quad * 4] = w2;
        }
        // q last: its MFMAs overlap the k/v store stragglers before B1
        short8 hf0 = *(const short8*)&sm[OH + t_my * ST + quad * 8];
        short8 hf1 = *(const short8*)&sm[OH + t_my * ST + 32 + quad * 8];
#pragma unroll
        for (int jt = 0; jt < 4; ++jt) {           // q: stays in registers (own rows)
            f32x4 a = mfma16(WB[(size_t)(jt * 2 + 0) * 64 + lane], hf0, zf);
            a = mfma16(WB[(size_t)(jt * 2 + 1) * 64 + lane], hf1, a);
            qp[jt * 2 + 0] = pk2(a[0], a[1]);
            qp[jt * 2 + 1] = pk2(a[2], a[3]);
        }
    }
    __syncthreads();   // B1: k, vT, ones row read across waves in attention

    // ---------- phase 3: attention, S^T scheme, zero barriers ----------
    const bool keep0 = (quad * 4 + 0) <= nn, keep1 = (quad * 4 + 1) <= nn;
    const bool keep2 = (quad * 4 + 2) <= nn, keep3 = (quad * 4 + 3) <= nn;
    const int arow_base = (nn < 8) ? nn : 64;      // lanes 8..15 read ones row (rows 9..15 unused)
    const int arow_step = (nn < 8) ? 8 : 0;
    const int nks = (wv < 2) ? 1 : 2;      // PV K-range: s < nks*32 covers all unmasked s
    const int zhi = nks * 2;               // P tiles PV reads but QK never writes: zero ONCE
    for (int mt = wv + 1; mt < zhi; ++mt) {
        uint2 w; w.x = 0u; w.y = 0u;
        *(uint2*)&sm[OP + t_my * ST + mt * 16 + quad * 4] = w;
    }
    // hoist: build ALL heads' q B-frags up front — 32 bpermutes issue
    // back-to-back (pipelined) instead of inside each head's dep chain.
    short8 bq8[8];
#pragma unroll
    for (int h = 0; h < 8; ++h) {
        int qsA = ((h & 1) * 2) * 16 + nn, qsB = qsA + 16;
        int qi = (h >> 1) * 2;
        union { unsigned u[4]; short8 s; } bb;
        bb.u[0] = __shfl(qp[qi + 0], qsA);
        bb.u[1] = __shfl(qp[qi + 1], qsA);
        bb.u[2] = __shfl(qp[qi + 0], qsB);
        bb.u[3] = __shfl(qp[qi + 1], qsB);
        bq8[h] = bb.s;
    }
#pragma unroll 2
    for (int h = 0; h < 8; ++h) {
        const short8 bq = bq8[h];
        // QK^T tiles, fully unrolled with wave-uniform guards (causal skip)
#pragma unroll
        for (int mt = 0; mt < 4; ++mt) {
            if (mt <= wv) {
                short8 ak = z8;
                if (quad == 0) ak = *(const short8*)&sm[OKK + (mt * 16 + nn) * ST + h * 8];
                f32x4 s = mfma16(ak, bq, zf);      // S^T[s][t], rows s, col t=t_my
                float e0 = EXP2F(s[0]), e1 = EXP2F(s[1]), e2 = EXP2F(s[2]), e3 = EXP2F(s[3]);
                if (mt == wv) {                    // diagonal tile: apply causal mask
                    e0 = keep0 ? e0 : 0.f; e1 = keep1 ? e1 : 0.f;
                    e2 = keep2 ? e2 : 0.f; e3 = keep3 ? e3 : 0.f;
                }
                uint2 w; w.x = pk2(e0, e1); w.y = pk2(e2, e3);
                *(uint2*)&sm[OP + t_my * ST + mt * 16 + quad * 4] = w;
            }
        }
        // PV: A = vT rows (d<8) + ones row (m=8) -> C row 8 = row-sum (denominator)
        const int arow = arow_base + h * arow_step;
        f32x4 pv = zf;
#pragma unroll
        for (int ks = 0; ks < 2; ++ks) {
            if (ks < nks) {
                short8 av = *(const short8*)&sm[OV + arow * ST + ks * 32 + quad * 8];
                short8 bp = *(const short8*)&sm[OP + t_my * ST + ks * 32 + quad * 8];
                pv = mfma16(av, bp, pv);
            }
        }
        float denom = __shfl(pv[0], 32 + nn);      // row m=8 lives at quad 2, reg 0
        float rd = RCPF(denom);
        if (quad < 2) {                            // valid d = quad*4+r in 0..7
            uint2 w; w.x = pk2(pv[0] * rd, pv[1] * rd); w.y = pk2(pv[2] * rd, pv[3] * rd);
            *(uint2*)&sm[OH + t_my * ST + h * 8 + quad * 4] = w;   // a16[t][h*8+d]
        }
    }

    // ---------- phase 4: Wo + residual + LN2 (all wave-private; no barrier) ----------
    {
        short8 aa0 = *(const short8*)&sm[OH + t_my * ST + quad * 8];
        short8 aa1 = *(const short8*)&sm[OH + t_my * ST + 32 + quad * 8];
#pragma unroll
        for (int nt = 0; nt < 4; ++nt) {
            f32x4 oa = mfma16(aa0, WB[(size_t)(24 + nt * 2 + 0) * 64 + lane], zf);
            oa = mfma16(aa1, WB[(size_t)(24 + nt * 2 + 1) * 64 + lane], oa);
            float bov = bo[nt * 16 + nn];
#pragma unroll
            for (int r = 0; r < 4; ++r) xr[nt * 4 + r] += oa[r] + bov;
        }
    }
#pragma unroll
    for (int nt = 0; nt < 4; ++nt) { gv[nt] = g2[nt * 16 + nn]; bv[nt] = be2[nt * 16 + nn]; }
#pragma unroll
    for (int r = 0; r < 4; ++r) {
        float s1 = 0.f, s2 = 0.f;
#pragma unroll
        for (int nt = 0; nt < 4; ++nt) { float v = xr[nt * 4 + r]; s1 += v; s2 += v * v; }
        s1 += __shfl_xor(s1, 1); s1 += __shfl_xor(s1, 2); s1 += __shfl_xor(s1, 4); s1 += __shfl_xor(s1, 8);
        s2 += __shfl_xor(s2, 1); s2 += __shfl_xor(s2, 2); s2 += __shfl_xor(s2, 4); s2 += __shfl_xor(s2, 8);
        float mu = s1 * 0.015625f;
        float rstd = rsqrtf(s2 * 0.015625f - mu * mu + 1e-5f);
        int base = OP + (wv * 16 + quad * 4 + r) * ST + nn;   // h2 into dead P region
        float h0 = (xr[0 + r]  - mu) * rstd * gv[0] + bv[0];
        float h1 = (xr[4 + r]  - mu) * rstd * gv[1] + bv[1];
        float h2 = (xr[8 + r]  - mu) * rstd * gv[2] + bv[2];
        float h3 = (xr[12 + r] - mu) * rstd * gv[3] + bv[3];
        unsigned pA = pk2(h0, h1), pB = pk2(h2, h3);
        sm[base +  0] = (short)pA;
        sm[base + 16] = (short)(pA >> 16);
        sm[base + 32] = (short)pB;
        sm[base + 48] = (short)(pB >> 16);
    }
    __syncthreads();   // B2: h2 visible (FF1 col-part reads all rows); attn reads done

    // ---------- phase 5: FF col-partitioned, 2 K-chunks of 128 ----------
    short8 h2r[4][2];                      // h2 row-frags for all 4 row-tiles (static idx)
#pragma unroll
    for (int rt = 0; rt < 4; ++rt) {
        h2r[rt][0] = *(const short8*)&sm[OP + (rt * 16 + nn) * ST + quad * 8];
        h2r[rt][1] = *(const short8*)&sm[OP + (rt * 16 + nn) * ST + 32 + quad * 8];
    }
    f32x4 fa[4];                           // y[all rows][own 16 cols]: fa[rt][r]
#pragma unroll
    for (int rt = 0; rt < 4; ++rt) fa[rt] = zf;
#pragma unroll
    for (int c = 0; c < 2; ++c) {
        // FF1: this wave's 2 col-tiles of the chunk, all 64 rows (2 frags/tile)
#pragma unroll
        for (int g = 0; g < 2; ++g) {
            int gc = c * 8 + wv * 2 + g;           // global 16-col tile
            int fid = 32 + (gc >> 2) * 8 + (gc & 3) * 2;
            short8 wf0 = WB[(size_t)fid * 64 + lane];
            short8 wf1 = WB[(size_t)(fid + 1) * 64 + lane];
            const float4 bb = *(const float4*)&b1[gc * 16 + quad * 4];
#pragma unroll
            for (int rt = 0; rt < 4; ++rt) {
                f32x4 u = mfma16(wf0, h2r[rt][0], zf);
                u = mfma16(wf1, h2r[rt][1], u);
                float u0 = fmaxf(u[0] + bb.x, 0.f), u1 = fmaxf(u[1] + bb.y, 0.f);
                float u2 = fmaxf(u[2] + bb.z, 0.f), u3 = fmaxf(u[3] + bb.w, 0.f);
                uint2 w; w.x = pk2(u0, u1); w.y = pk2(u2, u3);
                *(uint2*)&sm[OU + (rt * 16 + nn) * STU + (wv * 2 + g) * 16 + quad * 4] = w;
            }
        }
        __syncthreads();   // u chunk ready (written col-split by all waves)
        // FF2: own 16 output cols, all rows, K=128 of this chunk (4 frags)
#pragma unroll
        for (int kl = 0; kl < 4; ++kl) {
            int fidb = 64 + (c * 2 + (kl >> 1)) * 8 + wv * 2 + (kl & 1);
            short8 w2f = WB[(size_t)fidb * 64 + lane];
#pragma unroll
            for (int rt = 0; rt < 4; ++rt) {
                short8 au = *(const short8*)&sm[OU + (rt * 16 + nn) * STU + kl * 32 + quad * 8];
                fa[rt] = mfma16(au, w2f, fa[rt]);
            }
        }
        if (c == 0) __syncthreads();   // u reads done before chunk 1 overwrites
    }
    // ---------- y (f32) through LDS to row owners: cols 0..31 -> OH, 32..63 -> OP ----
    {
        float* yr = (wv < 2) ? (float*)sm : (float*)(sm + OP);
        const int ycol = (wv & 1) * 16 + nn;
#pragma unroll
        for (int rt = 0; rt < 4; ++rt)
#pragma unroll
            for (int r = 0; r < 4; ++r)
                yr[(rt * 16 + quad * 4 + r) * 34 + ycol] = fa[rt][r];
    }
    __syncthreads();   // y ready

    // ---------- phase 6: out = xr + y + b2 ----------
    float* ob = out + (size_t)b * 4096;
    const float* yA = (const float*)sm;
    const float* yB = (const float*)(sm + OP);
#pragma unroll
    for (int nt = 0; nt < 4; ++nt) {
        const float* ys = (nt < 2) ? yA : yB;
        float b2v = b2[nt * 16 + nn];
#pragma unroll
        for (int r = 0; r < 4; ++r) {
            float yv = ys[(wv * 16 + quad * 4 + r) * 34 + (nt & 1) * 16 + nn];
            ob[(wv * 16 + quad * 4 + r) * 64 + nt * 16 + nn] = xr[nt * 4 + r] + yv + b2v;
        }
    }
}

extern "C" void kernel_launch(void* const* d_in, const int* in_sizes, int n_in,
                              void* d_out, int out_size, void* d_ws, size_t ws_size,
                              hipStream_t stream) {
    const float* x   = (const float*)d_in[0];
    const float* Wq  = (const float*)d_in[1];
    const float* Wk  = (const float*)d_in[2];
    const float* Wv  = (const float*)d_in[3];
    const float* Wo  = (const float*)d_in[4];
    const float* bo  = (const float*)d_in[5];
    const float* W1  = (const float*)d_in[6];
    const float* b1  = (const float*)d_in[7];
    const float* W2  = (const float*)d_in[8];
    const float* b2  = (const float*)d_in[9];
    const float* g1  = (const float*)d_in[10];
    const float* be1 = (const float*)d_in[11];
    const float* g2  = (const float*)d_in[12];
    const float* be2 = (const float*)d_in[13];
    short* ws = (short*)d_ws;
    prepack_kernel<<<dim3(96), dim3(64), 0, stream>>>(Wq, Wk, Wv, Wo, W1, W2, ws);
    const int nb = in_sizes[0] / 4096;
    block_kernel<<<dim3(nb), dim3(256), 0, stream>>>(
        x, bo, b1, b2, g1, be1, g2, be2, (const short8*)ws, (float*)d_out);
}

// Round 10
// 193.421 us; speedup vs baseline: 1.9384x; 1.9384x over previous
//
#include <hip/hip_runtime.h>
#include <hip/hip_bf16.h>

// Transformer block B=4096,T=64,C=64,H=8,hs=8,FF=256. fp32 in/out, bf16 MFMA.
// One batch/block, 4 waves; wave w owns rows t in [16w,16w+16).
// mfma_f32_16x16x32_bf16: C col=lane&15,row=quad*4+reg; A[m=lane&15][k=quad*8+j];
// B[k=quad*8+j][n=lane&15]. A-frag and B-frag share the same lane->W[k][col] map.
// R15 = R14 with the head loop FULLY unrolled. R14's `unroll 2` left h runtime
// -> bq8[h] runtime-indexed ext_vector -> scratch (rule #20): +31MB write/+11MB
// fetch spill traffic, 286us. Full unroll makes every bq8 access static (R13
// proved this codegen spill-free). P stride 72 (correct; stride-40 aliasing
// fixed in R14, absmax 0.031). k/v before q in phase 2; bq8 hoist. LDS 37008B,
// 4 blocks/CU. Barriers: 7.

typedef __attribute__((ext_vector_type(8))) short short8;
typedef __attribute__((ext_vector_type(4))) float f32x4;

#if __has_builtin(__builtin_amdgcn_exp2f)
#define EXP2F(x) __builtin_amdgcn_exp2f(x)
#else
#define EXP2F(x) __expf((x) * 0.69314718056f)
#endif
#if __has_builtin(__builtin_amdgcn_rcpf)
#define RCPF(x) __builtin_amdgcn_rcpf(x)
#else
#define RCPF(x) (1.0f / (x))
#endif

#define ST  72           // row stride in shorts (144 B) for h/k/vT/P
#define STU 136          // u chunk row stride (272 B)
#define OH  0            // h(LN1) [64][ST]; then a16; then y cols 0..31 (f32 [64][34])
#define OKK 4608         // k [64][ST]
#define OV  9216         // vT rows 0..63 + ones row 64 (65 x ST, ends 13896)
#define OP  13896        // P [64][ST] single; later h2; later y cols 32..63 (f32 [64][34])
#define OU  4608         // u chunk [64][STU] (overlays k,vT after attention; ends 13312)
#define NSH 18504        // shorts = 37008 B -> 4 blocks/CU

__device__ __forceinline__ short f2bf(float f) {
    unsigned int u = __float_as_uint(f);
    u += 0x7fffu + ((u >> 16) & 1u);
    return (short)(u >> 16);
}
__device__ __forceinline__ unsigned pk2(float a, float b) {
    float2 t; t.x = a; t.y = b;
    __hip_bfloat162 h = __float22bfloat162_rn(t);
    unsigned u; __builtin_memcpy(&u, &h, 4); return u;
}
__device__ __forceinline__ f32x4 mfma16(short8 a, short8 b, f32x4 c) {
    return __builtin_amdgcn_mfma_f32_16x16x32_bf16(a, b, c, 0, 0, 0);
}

// ---- weight pre-pack: fp32 -> bf16 frag order (Wq pre-scaled by 1/8*log2e) ----
// fid 0..23: QKV (tile*2+ks; 0..3 Wq,4..7 Wk,8..11 Wv); 24..31: Wo; 32..63: W1; 64..95: W2
__global__ __launch_bounds__(64) void prepack_kernel(
    const float* __restrict__ Wq, const float* __restrict__ Wk,
    const float* __restrict__ Wv, const float* __restrict__ Wo,
    const float* __restrict__ W1, const float* __restrict__ W2,
    short* __restrict__ ws)
{
    int gid = blockIdx.x * 64 + threadIdx.x;       // 96 blocks * 64 = 96 fids * 64 lanes
    int lane = gid & 63;
    int fid  = gid >> 6;
    int quad = lane >> 4, nn = lane & 15;
    short8 o;
    if (fid < 24) {
        int tile = fid >> 1, ks = fid & 1;
        const float* Ws = (tile < 4) ? Wq : ((tile < 8) ? Wk : Wv);
        float scale = (tile < 4) ? 0.18033688011f : 1.0f;   // 1/8 * log2(e) folded into q
        int col = (tile & 3) * 16 + nn;
#pragma unroll
        for (int j = 0; j < 8; ++j)
            o[j] = f2bf(Ws[(ks * 32 + quad * 8 + j) * 64 + col] * scale);
    } else if (fid < 32) {
        int idx = fid - 24, nt = idx >> 1, ks = idx & 1;
#pragma unroll
        for (int j = 0; j < 8; ++j)
            o[j] = f2bf(Wo[(ks * 32 + quad * 8 + j) * 64 + nt * 16 + nn]);
    } else if (fid < 64) {
        int idx = fid - 32, c = idx >> 3, tile = (idx >> 1) & 3, ks = idx & 1;
#pragma unroll
        for (int j = 0; j < 8; ++j)
            o[j] = f2bf(W1[(ks * 32 + quad * 8 + j) * 256 + c * 64 + tile * 16 + nn]);
    } else {
        int idx = fid - 64, c = idx >> 3, nt = (idx >> 1) & 3, ks = idx & 1;
#pragma unroll
        for (int j = 0; j < 8; ++j)
            o[j] = f2bf(W2[(c * 64 + ks * 32 + quad * 8 + j) * 64 + nt * 16 + nn]);
    }
    *(short8*)(ws + (size_t)gid * 8) = o;
}

__global__ __launch_bounds__(256, 4) void block_kernel(
    const float* __restrict__ x,
    const float* __restrict__ bo,
    const float* __restrict__ b1,
    const float* __restrict__ b2,
    const float* __restrict__ g1, const float* __restrict__ be1,
    const float* __restrict__ g2, const float* __restrict__ be2,
    const short8* __restrict__ WB,
    float* __restrict__ out)
{
    __shared__ short sm[NSH];
    const int tid  = threadIdx.x;
    const int wv   = tid >> 6;
    const int lane = tid & 63;
    const int quad = lane >> 4;
    const int nn   = lane & 15;
    const int t_my = wv * 16 + nn;        // column-owned row index for swapped products
    const int b    = blockIdx.x;
    const float* xb = x + (size_t)b * 4096;
    const f32x4 zf = {0.f, 0.f, 0.f, 0.f};
    const short8 z8 = {0, 0, 0, 0, 0, 0, 0, 0};

    // ---------- phase 1: x -> regs (C-layout), LN1 -> h; init ones row ----------
    if (tid < ST) sm[OV + 64 * ST + tid] = (short)0x3F80;   // ones row (m=8 of PV A)
    float xr[16];                          // xr[nt*4+r] = x[16wv+quad*4+r][nt*16+nn]
    float gv[4], bv[4];
#pragma unroll
    for (int nt = 0; nt < 4; ++nt) { gv[nt] = g1[nt * 16 + nn]; bv[nt] = be1[nt * 16 + nn]; }
#pragma unroll
    for (int nt = 0; nt < 4; ++nt)
#pragma unroll
        for (int r = 0; r < 4; ++r)
            xr[nt * 4 + r] = xb[(wv * 16 + quad * 4 + r) * 64 + nt * 16 + nn];
#pragma unroll
    for (int r = 0; r < 4; ++r) {
        float s1 = 0.f, s2 = 0.f;
#pragma unroll
        for (int nt = 0; nt < 4; ++nt) { float v = xr[nt * 4 + r]; s1 += v; s2 += v * v; }
        s1 += __shfl_xor(s1, 1); s1 += __shfl_xor(s1, 2); s1 += __shfl_xor(s1, 4); s1 += __shfl_xor(s1, 8);
        s2 += __shfl_xor(s2, 1); s2 += __shfl_xor(s2, 2); s2 += __shfl_xor(s2, 4); s2 += __shfl_xor(s2, 8);
        float mu = s1 * 0.015625f;
        float rstd = rsqrtf(s2 * 0.015625f - mu * mu + 1e-5f);
        int base = OH + (wv * 16 + quad * 4 + r) * ST + nn;
        float h0 = (xr[0 + r]  - mu) * rstd * gv[0] + bv[0];
        float h1 = (xr[4 + r]  - mu) * rstd * gv[1] + bv[1];
        float h2 = (xr[8 + r]  - mu) * rstd * gv[2] + bv[2];
        float h3 = (xr[12 + r] - mu) * rstd * gv[3] + bv[3];
        unsigned pA = pk2(h0, h1), pB = pk2(h2, h3);
        sm[base +  0] = (short)pA;
        sm[base + 16] = (short)(pA >> 16);
        sm[base + 32] = (short)pB;
        sm[base + 48] = (short)(pB >> 16);
    }
    __syncthreads();   // B0: h visible to all waves (k/v col-partition reads all rows)

    // ---------- phase 2: k/v (LDS, col-part: 2 frags each), then q (regs) ----------
    unsigned qp[8];                        // qp[jt*2+p] = bf16 pair q[t_my][jt*16+quad*4+2p..+1]
    {
        // weight frags for this wave's k/v column slice: load ONCE, reuse over 4 row-tiles
        const short8 wk0 = WB[(size_t)((4 + wv) * 2 + 0) * 64 + lane];
        const short8 wk1 = WB[(size_t)((4 + wv) * 2 + 1) * 64 + lane];
        const short8 wv0 = WB[(size_t)((8 + wv) * 2 + 0) * 64 + lane];
        const short8 wv1 = WB[(size_t)((8 + wv) * 2 + 1) * 64 + lane];
#pragma unroll
        for (int rt = 0; rt < 4; ++rt) {           // k,v for ALL rows, own col-slice
            short8 hA = *(const short8*)&sm[OH + (rt * 16 + nn) * ST + quad * 8];
            short8 hB = *(const short8*)&sm[OH + (rt * 16 + nn) * ST + 32 + quad * 8];
            // k cols wv*16..+15: C[m=kcol][n=t] -> store k[t][kcol]
            f32x4 ka = mfma16(wk0, hA, zf); ka = mfma16(wk1, hB, ka);
            uint2 w1; w1.x = pk2(ka[0], ka[1]); w1.y = pk2(ka[2], ka[3]);
            *(uint2*)&sm[OKK + (rt * 16 + nn) * ST + wv * 16 + quad * 4] = w1;
            // v cols wv*16..+15: C[m=t][n=vcol] -> store vT[vcol][t]
            f32x4 va = mfma16(hA, wv0, zf); va = mfma16(hB, wv1, va);
            uint2 w2; w2.x = pk2(va[0], va[1]); w2.y = pk2(va[2], va[3]);
            *(uint2*)&sm[OV + (wv * 16 + nn) * ST + rt * 16 + quad * 4] = w2;
        }
        // q last: its MFMAs overlap the k/v store stragglers before B1
        short8 hf0 = *(const short8*)&sm[OH + t_my * ST + quad * 8];
        short8 hf1 = *(const short8*)&sm[OH + t_my * ST + 32 + quad * 8];
#pragma unroll
        for (int jt = 0; jt < 4; ++jt) {           // q: stays in registers (own rows)
            f32x4 a = mfma16(WB[(size_t)(jt * 2 + 0) * 64 + lane], hf0, zf);
            a = mfma16(WB[(size_t)(jt * 2 + 1) * 64 + lane], hf1, a);
            qp[jt * 2 + 0] = pk2(a[0], a[1]);
            qp[jt * 2 + 1] = pk2(a[2], a[3]);
        }
    }
    __syncthreads();   // B1: k, vT, ones row read across waves in attention

    // ---------- phase 3: attention, S^T scheme, zero barriers ----------
    const bool keep0 = (quad * 4 + 0) <= nn, keep1 = (quad * 4 + 1) <= nn;
    const bool keep2 = (quad * 4 + 2) <= nn, keep3 = (quad * 4 + 3) <= nn;
    const int arow_base = (nn < 8) ? nn : 64;      // lanes 8..15 read ones row (rows 9..15 unused)
    const int arow_step = (nn < 8) ? 8 : 0;
    const int nks = (wv < 2) ? 1 : 2;      // PV K-range: s < nks*32 covers all unmasked s
    const int zhi = nks * 2;               // P tiles PV reads but QK never writes: zero ONCE
    for (int mt = wv + 1; mt < zhi; ++mt) {
        uint2 w; w.x = 0u; w.y = 0u;
        *(uint2*)&sm[OP + t_my * ST + mt * 16 + quad * 4] = w;
    }
    // hoist: build ALL heads' q B-frags up front — 32 bpermutes issue
    // back-to-back (pipelined) instead of inside each head's dep chain.
    short8 bq8[8];
#pragma unroll
    for (int h = 0; h < 8; ++h) {
        int qsA = ((h & 1) * 2) * 16 + nn, qsB = qsA + 16;
        int qi = (h >> 1) * 2;
        union { unsigned u[4]; short8 s; } bb;
        bb.u[0] = __shfl(qp[qi + 0], qsA);
        bb.u[1] = __shfl(qp[qi + 1], qsA);
        bb.u[2] = __shfl(qp[qi + 0], qsB);
        bb.u[3] = __shfl(qp[qi + 1], qsB);
        bq8[h] = bb.s;
    }
    // FULL unroll: h must be compile-time so bq8[h] stays in registers (rule #20;
    // R14's unroll-2 made it runtime-indexed -> scratch -> 3x regression).
#pragma unroll
    for (int h = 0; h < 8; ++h) {
        const short8 bq = bq8[h];
        // QK^T tiles, fully unrolled with wave-uniform guards (causal skip)
#pragma unroll
        for (int mt = 0; mt < 4; ++mt) {
            if (mt <= wv) {
                short8 ak = z8;
                if (quad == 0) ak = *(const short8*)&sm[OKK + (mt * 16 + nn) * ST + h * 8];
                f32x4 s = mfma16(ak, bq, zf);      // S^T[s][t], rows s, col t=t_my
                float e0 = EXP2F(s[0]), e1 = EXP2F(s[1]), e2 = EXP2F(s[2]), e3 = EXP2F(s[3]);
                if (mt == wv) {                    // diagonal tile: apply causal mask
                    e0 = keep0 ? e0 : 0.f; e1 = keep1 ? e1 : 0.f;
                    e2 = keep2 ? e2 : 0.f; e3 = keep3 ? e3 : 0.f;
                }
                uint2 w; w.x = pk2(e0, e1); w.y = pk2(e2, e3);
                *(uint2*)&sm[OP + t_my * ST + mt * 16 + quad * 4] = w;
            }
        }
        // PV: A = vT rows (d<8) + ones row (m=8) -> C row 8 = row-sum (denominator)
        const int arow = arow_base + h * arow_step;
        f32x4 pv = zf;
#pragma unroll
        for (int ks = 0; ks < 2; ++ks) {
            if (ks < nks) {
                short8 av = *(const short8*)&sm[OV + arow * ST + ks * 32 + quad * 8];
                short8 bp = *(const short8*)&sm[OP + t_my * ST + ks * 32 + quad * 8];
                pv = mfma16(av, bp, pv);
            }
        }
        float denom = __shfl(pv[0], 32 + nn);      // row m=8 lives at quad 2, reg 0
        float rd = RCPF(denom);
        if (quad < 2) {                            // valid d = quad*4+r in 0..7
            uint2 w; w.x = pk2(pv[0] * rd, pv[1] * rd); w.y = pk2(pv[2] * rd, pv[3] * rd);
            *(uint2*)&sm[OH + t_my * ST + h * 8 + quad * 4] = w;   // a16[t][h*8+d]
        }
    }

    // ---------- phase 4: Wo + residual + LN2 (all wave-private; no barrier) ----------
    {
        short8 aa0 = *(const short8*)&sm[OH + t_my * ST + quad * 8];
        short8 aa1 = *(const short8*)&sm[OH + t_my * ST + 32 + quad * 8];
#pragma unroll
        for (int nt = 0; nt < 4; ++nt) {
            f32x4 oa = mfma16(aa0, WB[(size_t)(24 + nt * 2 + 0) * 64 + lane], zf);
            oa = mfma16(aa1, WB[(size_t)(24 + nt * 2 + 1) * 64 + lane], oa);
            float bov = bo[nt * 16 + nn];
#pragma unroll
            for (int r = 0; r < 4; ++r) xr[nt * 4 + r] += oa[r] + bov;
        }
    }
#pragma unroll
    for (int nt = 0; nt < 4; ++nt) { gv[nt] = g2[nt * 16 + nn]; bv[nt] = be2[nt * 16 + nn]; }
#pragma unroll
    for (int r = 0; r < 4; ++r) {
        float s1 = 0.f, s2 = 0.f;
#pragma unroll
        for (int nt = 0; nt < 4; ++nt) { float v = xr[nt * 4 + r]; s1 += v; s2 += v * v; }
        s1 += __shfl_xor(s1, 1); s1 += __shfl_xor(s1, 2); s1 += __shfl_xor(s1, 4); s1 += __shfl_xor(s1, 8);
        s2 += __shfl_xor(s2, 1); s2 += __shfl_xor(s2, 2); s2 += __shfl_xor(s2, 4); s2 += __shfl_xor(s2, 8);
        float mu = s1 * 0.015625f;
        float rstd = rsqrtf(s2 * 0.015625f - mu * mu + 1e-5f);
        int base = OP + (wv * 16 + quad * 4 + r) * ST + nn;   // h2 into dead P region
        float h0 = (xr[0 + r]  - mu) * rstd * gv[0] + bv[0];
        float h1 = (xr[4 + r]  - mu) * rstd * gv[1] + bv[1];
        float h2 = (xr[8 + r]  - mu) * rstd * gv[2] + bv[2];
        float h3 = (xr[12 + r] - mu) * rstd * gv[3] + bv[3];
        unsigned pA = pk2(h0, h1), pB = pk2(h2, h3);
        sm[base +  0] = (short)pA;
        sm[base + 16] = (short)(pA >> 16);
        sm[base + 32] = (short)pB;
        sm[base + 48] = (short)(pB >> 16);
    }
    __syncthreads();   // B2: h2 visible (FF1 col-part reads all rows); attn reads done

    // ---------- phase 5: FF col-partitioned, 2 K-chunks of 128 ----------
    short8 h2r[4][2];                      // h2 row-frags for all 4 row-tiles (static idx)
#pragma unroll
    for (int rt = 0; rt < 4; ++rt) {
        h2r[rt][0] = *(const short8*)&sm[OP + (rt * 16 + nn) * ST + quad * 8];
        h2r[rt][1] = *(const short8*)&sm[OP + (rt * 16 + nn) * ST + 32 + quad * 8];
    }
    f32x4 fa[4];                           // y[all rows][own 16 cols]: fa[rt][r]
#pragma unroll
    for (int rt = 0; rt < 4; ++rt) fa[rt] = zf;
#pragma unroll
    for (int c = 0; c < 2; ++c) {
        // FF1: this wave's 2 col-tiles of the chunk, all 64 rows (2 frags/tile)
#pragma unroll
        for (int g = 0; g < 2; ++g) {
            int gc = c * 8 + wv * 2 + g;           // global 16-col tile
            int fid = 32 + (gc >> 2) * 8 + (gc & 3) * 2;
            short8 wf0 = WB[(size_t)fid * 64 + lane];
            short8 wf1 = WB[(size_t)(fid + 1) * 64 + lane];
            const float4 bb = *(const float4*)&b1[gc * 16 + quad * 4];
#pragma unroll
            for (int rt = 0; rt < 4; ++rt) {
                f32x4 u = mfma16(wf0, h2r[rt][0], zf);
                u = mfma16(wf1, h2r[rt][1], u);
                float u0 = fmaxf(u[0] + bb.x, 0.f), u1 = fmaxf(u[1] + bb.y, 0.f);
                float u2 = fmaxf(u[2] + bb.z, 0.f), u3 = fmaxf(u[3] + bb.w, 0.f);
                uint2 w; w.x = pk2(u0, u1); w.y = pk2(u2, u3);
                *(uint2*)&sm[OU + (rt * 16 + nn) * STU + (wv * 2 + g) * 16 + quad * 4] = w;
            }
        }
        __syncthreads();   // u chunk ready (written col-split by all waves)
        // FF2: own 16 output cols, all rows, K=128 of this chunk (4 frags)
#pragma unroll
        for (int kl = 0; kl < 4; ++kl) {
            int fidb = 64 + (c * 2 + (kl >> 1)) * 8 + wv * 2 + (kl & 1);
            short8 w2f = WB[(size_t)fidb * 64 + lane];
#pragma unroll
            for (int rt = 0; rt < 4; ++rt) {
                short8 au = *(const short8*)&sm[OU + (rt * 16 + nn) * STU + kl * 32 + quad * 8];
                fa[rt] = mfma16(au, w2f, fa[rt]);
            }
        }
        if (c == 0) __syncthreads();   // u reads done before chunk 1 overwrites
    }
    // ---------- y (f32) through LDS to row owners: cols 0..31 -> OH, 32..63 -> OP ----
    {
        float* yr = (wv < 2) ? (float*)sm : (float*)(sm + OP);
        const int ycol = (wv & 1) * 16 + nn;
#pragma unroll
        for (int rt = 0; rt < 4; ++rt)
#pragma unroll
            for (int r = 0; r < 4; ++r)
                yr[(rt * 16 + quad * 4 + r) * 34 + ycol] = fa[rt][r];
    }
    __syncthreads();   // y ready

    // ---------- phase 6: out = xr + y + b2 ----------
    float* ob = out + (size_t)b * 4096;
    const float* yA = (const float*)sm;
    const float* yB = (const float*)(sm + OP);
#pragma unroll
    for (int nt = 0; nt < 4; ++nt) {
        const float* ys = (nt < 2) ? yA : yB;
        float b2v = b2[nt * 16 + nn];
#pragma unroll
        for (int r = 0; r < 4; ++r) {
            float yv = ys[(wv * 16 + quad * 4 + r) * 34 + (nt & 1) * 16 + nn];
            ob[(wv * 16 + quad * 4 + r) * 64 + nt * 16 + nn] = xr[nt * 4 + r] + yv + b2v;
        }
    }
}

extern "C" void kernel_launch(void* const* d_in, const int* in_sizes, int n_in,
                              void* d_out, int out_size, void* d_ws, size_t ws_size,
                              hipStream_t stream) {
    const float* x   = (const float*)d_in[0];
    const float* Wq  = (const float*)d_in[1];
    const float* Wk  = (const float*)d_in[2];
    const float* Wv  = (const float*)d_in[3];
    const float* Wo  = (const float*)d_in[4];
    const float* bo  = (const float*)d_in[5];
    const float* W1  = (const float*)d_in[6];
    const float* b1  = (const float*)d_in[7];
    const float* W2  = (const float*)d_in[8];
    const float* b2  = (const float*)d_in[9];
    const float* g1  = (const float*)d_in[10];
    const float* be1 = (const float*)d_in[11];
    const float* g2  = (const float*)d_in[12];
    const float* be2 = (const float*)d_in[13];
    short* ws = (short*)d_ws;
    prepack_kernel<<<dim3(96), dim3(64), 0, stream>>>(Wq, Wk, Wv, Wo, W1, W2, ws);
    const int nb = in_sizes[0] / 4096;
    block_kernel<<<dim3(nb), dim3(256), 0, stream>>>(
        x, bo, b1, b2, g1, be1, g2, be2, (const short8*)ws, (float*)d_out);
}